// Round 5
// baseline (455.703 us; speedup 1.0000x reference)
//
#include <hip/hip_runtime.h>
#include <hip/hip_fp16.h>

#define N_NODES 100000
#define N_EDGES 1600000
#define EMAX2   2000000                 // pad-4 edge capacity (1.6M + <=3*100K)
#define N_GRAPHS 2048
#define HID 64
#define IN_F 14
#define N_CLS 2
#define EPS 1e-5f

#define BSHIFT 9
#define NBUCK 196                       // ceil(100000 / 512)
#define ABLOCKS 256
#define CHUNK (N_EDGES / ABLOCKS)       // 6250, exact

#define NBLK2 128                       // node-sort blocks
#define NCHUNK2 ((N_NODES + NBLK2 - 1) / NBLK2)  // 782

#define NQUADS 8192                     // gather quads per feature group

typedef _Float16 half_t;
typedef _Float16 half8 __attribute__((ext_vector_type(8)));
typedef float f32x4 __attribute__((ext_vector_type(4)));

#define GSTRIDE ((size_t)N_NODES * 16)  // halves per feature-group plane

// ============ CSR build, atomic-free (global) two-level counting sort ========

// histA + fold-in: zero gemb (atomic target of bn_relu_seg) and stats3.
__global__ __launch_bounds__(256) void histA_kernel(const int* __restrict__ col,
                                                    int* __restrict__ histG,
                                                    float* __restrict__ gemb,
                                                    float* __restrict__ stats3) {
    __shared__ int hl[NBUCK];
    for (int i = threadIdx.x; i < NBUCK; i += 256) hl[i] = 0;
    // zero gemb: 256 blocks x 512 floats = 2048*64
    for (int k = threadIdx.x; k < 512; k += 256)
        gemb[(size_t)blockIdx.x * 512 + k] = 0.f;
    if (blockIdx.x == 0 && threadIdx.x < 384) stats3[threadIdx.x] = 0.f;
    __syncthreads();
    int e0 = blockIdx.x * CHUNK;
    for (int e = e0 + threadIdx.x; e < e0 + CHUNK; e += 256)
        atomicAdd(&hl[col[e] >> BSHIFT], 1);
    __syncthreads();
    for (int i = threadIdx.x; i < NBUCK; i += 256)
        histG[i * ABLOCKS + blockIdx.x] = hl[i];
}

__global__ __launch_bounds__(256) void scanS1_kernel(const int* __restrict__ histG,
                                                     int* __restrict__ bsumA) {
    __shared__ int ls[256];
    ls[threadIdx.x] = histG[blockIdx.x * 256 + threadIdx.x];
    __syncthreads();
    for (int off = 128; off > 0; off >>= 1) {
        if (threadIdx.x < off) ls[threadIdx.x] += ls[threadIdx.x + off];
        __syncthreads();
    }
    if (threadIdx.x == 0) bsumA[blockIdx.x] = ls[0];
}

// scanS3 with fused bucket-level prefix (topscan merged): every block scans
// bsumA (raw sums) in LDS; bsumX gets the exclusive bucket prefix.
__global__ __launch_bounds__(256) void scanS3_kernel(int* __restrict__ histG,
                                                     const int* __restrict__ bsumA,
                                                     int* __restrict__ bsumX,
                                                     int* __restrict__ ptr) {
    __shared__ int ls[256], bs[256];
    int t = threadIdx.x;
    int rawB = (blockIdx.x < NBUCK) ? bsumA[blockIdx.x] : 0;
    bs[t] = (t < NBUCK) ? bsumA[t] : 0;
    int idx = blockIdx.x * 256 + t;
    int v = histG[idx];
    ls[t] = v;
    __syncthreads();
    for (int off = 1; off < 256; off <<= 1) {
        int x = ls[t];
        int y = bs[t];
        if (t >= off) { x += ls[t - off]; y += bs[t - off]; }
        __syncthreads();
        ls[t] = x; bs[t] = y;
        __syncthreads();
    }
    int bexcl = bs[blockIdx.x] - rawB;            // exclusive bucket prefix
    histG[idx] = ls[t] - v + bexcl;
    if (t == 0) bsumX[blockIdx.x] = bexcl;
    if (blockIdx.x == 0 && t == 0) ptr[N_NODES] = N_EDGES;
}

__global__ __launch_bounds__(256) void scatterA_kernel(const int* __restrict__ row,
                                                       const int* __restrict__ col,
                                                       const float* __restrict__ w,
                                                       const int* __restrict__ histG,
                                                       int2* __restrict__ EA) {
    __shared__ int cur[NBUCK];
    for (int i = threadIdx.x; i < NBUCK; i += 256)
        cur[i] = histG[i * ABLOCKS + blockIdx.x];
    __syncthreads();
    int e0 = blockIdx.x * CHUNK;
    for (int e = e0 + threadIdx.x; e < e0 + CHUNK; e += 256) {
        int c = col[e];
        int r = row[e];
        int fx = (int)__float2uint_rn(w[e] * 8192.0f);   // 15-bit fixed, exact for w=1
        int pos = atomicAdd(&cur[c >> BSHIFT], 1);        // LDS atomic
        EA[pos] = make_int2(r, (fx << 17) | c);
    }
}

// bucketA: per-bucket dense hist+scan -> ptr (unpadded CSR base), dinv
__global__ __launch_bounds__(256) void bucketA_kernel(const int2* __restrict__ EA,
                                                      const int* __restrict__ bsumX,
                                                      int* __restrict__ ptr,
                                                      float* __restrict__ dinv) {
    __shared__ int hist[512], wsum[512];
    int b = blockIdx.x;
    int beg = bsumX[b];
    int end = (b == NBUCK - 1) ? N_EDGES : bsumX[b + 1];
    int i0 = threadIdx.x, i1 = threadIdx.x + 256;
    hist[i0] = 0; hist[i1] = 0;
    wsum[i0] = 0; wsum[i1] = 0;
    __syncthreads();
    for (int e = beg + threadIdx.x; e < end; e += 256) {
        int2 ed = EA[e];
        int c9 = ed.y & 511;
        atomicAdd(&hist[c9], 1);
        atomicAdd(&wsum[c9], (int)((unsigned int)ed.y >> 17));
    }
    __syncthreads();
    int cnt0 = hist[i0], cnt1 = hist[i1];
    for (int off = 1; off < 512; off <<= 1) {
        int v0 = hist[i0], v1 = hist[i1];
        int a0 = (i0 >= off) ? hist[i0 - off] : 0;
        int a1 = (i1 >= off) ? hist[i1 - off] : 0;
        __syncthreads();
        hist[i0] = v0 + a0;
        hist[i1] = v1 + a1;
        __syncthreads();
    }
    int excl0 = hist[i0] - cnt0, excl1 = hist[i1] - cnt1;
    int col0 = (b << BSHIFT) + i0, col1 = (b << BSHIFT) + i1;
    if (col0 < N_NODES) {
        ptr[col0] = beg + excl0;
        dinv[col0] = rsqrtf(1.0f + (float)wsum[i0] * (1.0f / 8192.0f));
    }
    if (col1 < N_NODES) {
        ptr[col1] = beg + excl1;
        dinv[col1] = rsqrtf(1.0f + (float)wsum[i1] * (1.0f / 8192.0f));
    }
}

// ============ node degree sort (pad-4 edge layout) ===========================

__global__ __launch_bounds__(256) void histD_kernel(const int* __restrict__ ptr,
                                                    int* __restrict__ histD) {
    __shared__ int hl[2048];
    for (int i = threadIdx.x; i < 2048; i += 256) hl[i] = 0;
    __syncthreads();
    int n0 = blockIdx.x * NCHUNK2;
    int n1 = n0 + NCHUNK2; if (n1 > N_NODES) n1 = N_NODES;
    for (int n = n0 + threadIdx.x; n < n1; n += 256) {
        int d = ptr[n + 1] - ptr[n];
        if (d > 255) d = 255;
        atomicAdd(&hl[((threadIdx.x & 7) << 8) + d], 1);
    }
    __syncthreads();
    int s = 0;
#pragma unroll
    for (int c = 0; c < 8; c++) s += hl[(c << 8) + threadIdx.x];
    histD[threadIdx.x * NBLK2 + blockIdx.x] = s;
}

__global__ __launch_bounds__(128) void scanD1_kernel(const int* __restrict__ histD,
                                                     int* __restrict__ rowTot) {
    __shared__ int ls[128];
    ls[threadIdx.x] = histD[blockIdx.x * NBLK2 + threadIdx.x];
    __syncthreads();
    for (int off = 64; off > 0; off >>= 1) {
        if (threadIdx.x < off) ls[threadIdx.x] += ls[threadIdx.x + off];
        __syncthreads();
    }
    if (threadIdx.x == 0) rowTot[blockIdx.x] = ls[0];
}

// scanD3 with fused bin-level dual prefix (topscanD merged): every block
// (one per bin) scans rowTot in LDS for node counts + pad-4 edge counts;
// block 0 publishes nodeExcl/edgeExcl/ptrS[N] for scatterD.
__global__ __launch_bounds__(128) void scanD3_kernel(int* __restrict__ histD,
                                                     const int* __restrict__ rowTot,
                                                     int* __restrict__ nodeExcl,
                                                     int* __restrict__ edgeExcl,
                                                     int* __restrict__ ptrS) {
    __shared__ int ls[128], sa[256], sb[256];
    int t = threadIdx.x;
    int bin = blockIdx.x;
    int c0 = rowTot[t], c1 = rowTot[t + 128];
    sa[t] = c0;           sa[t + 128] = c1;
    sb[t] = c0 * ((t + 3) & ~3);
    sb[t + 128] = c1 * ((t + 131) & ~3);
    int idx = bin * NBLK2 + t;
    int v = histD[idx];
    ls[t] = v;
    __syncthreads();
    for (int off = 1; off < 256; off <<= 1) {     // 256-wide dual scan, 2/thread
        int a0 = sa[t], a1 = sa[t + 128];
        int b0 = sb[t], b1 = sb[t + 128];
        int x0 = (t >= off) ? sa[t - off] : 0;
        int x1 = (t + 128 >= off) ? sa[t + 128 - off] : 0;
        int y0 = (t >= off) ? sb[t - off] : 0;
        int y1 = (t + 128 >= off) ? sb[t + 128 - off] : 0;
        __syncthreads();
        sa[t] = a0 + x0; sa[t + 128] = a1 + x1;
        sb[t] = b0 + y0; sb[t + 128] = b1 + y1;
        __syncthreads();
    }
    for (int off = 1; off < 128; off <<= 1) {     // 128-wide histD column scan
        int x = ls[t];
        if (t >= off) x += ls[t - off];
        __syncthreads();
        ls[t] = x;
        __syncthreads();
    }
    int nE = sa[bin] - rowTot[bin];               // node-exclusive for this bin
    histD[idx] = ls[t] - v + nE;
    if (bin == 0) {
        nodeExcl[t] = sa[t] - rowTot[t];
        nodeExcl[t + 128] = sa[t + 128] - rowTot[t + 128];
        edgeExcl[t] = sb[t] - rowTot[t] * ((t + 3) & ~3);
        edgeExcl[t + 128] = sb[t + 128] - rowTot[t + 128] * ((t + 131) & ~3);
        if (t == 127) ptrS[N_NODES] = sb[255];    // total padded edges
    }
}

// scatterD + fold-in: zero the pad slots (srcoff/normh) so the big memset
// is unnecessary (only d..dpad-1 per node are pads; <=3 each).
__global__ __launch_bounds__(256) void scatterD_kernel(const int* __restrict__ ptr,
                                                       const int* __restrict__ histD,
                                                       const int* __restrict__ nodeExcl,
                                                       const int* __restrict__ edgeExcl,
                                                       int* __restrict__ perm,
                                                       int* __restrict__ ptrS,
                                                       int* __restrict__ newbase,
                                                       unsigned int* __restrict__ srcoff,
                                                       half_t* __restrict__ normh) {
    __shared__ int cur[256];
    cur[threadIdx.x] = histD[threadIdx.x * NBLK2 + blockIdx.x];
    __syncthreads();
    int n0 = blockIdx.x * NCHUNK2;
    int n1 = n0 + NCHUNK2; if (n1 > N_NODES) n1 = N_NODES;
    for (int n = n0 + threadIdx.x; n < n1; n += 256) {
        int d = ptr[n + 1] - ptr[n];
        if (d > 255) d = 255;
        int dpad = (d + 3) & ~3;
        int pos = atomicAdd(&cur[d], 1);                  // LDS atomic
        int ebase = edgeExcl[d] + (pos - nodeExcl[d]) * dpad;
        perm[pos] = n;
        ptrS[pos] = ebase;
        newbase[n] = ebase;
        for (int k = d; k < dpad; k++) {                  // zero pad slots
            srcoff[ebase + k] = 0u;
            normh[ebase + k] = (half_t)0.f;
        }
    }
}

// qbounds: edge-balanced contiguous node ranges for gather quads.
// Weight f(i) = ptrS[i] + 8*i (padded edges + per-node overhead), monotone.
__global__ __launch_bounds__(256) void qbounds_kernel(const int* __restrict__ ptrS,
                                                      int* __restrict__ qlo) {
    int q = blockIdx.x * 256 + threadIdx.x;
    if (q > NQUADS) return;
    if (q == NQUADS) { qlo[q] = N_NODES; return; }
    long long W = (long long)ptrS[N_NODES] + 8LL * N_NODES;
    long long target = (W * q) / NQUADS;
    int lo = 0, hi = N_NODES;
    while (lo < hi) {                                     // lower_bound on f(i)
        int mid = (lo + hi) >> 1;
        long long f = (long long)ptrS[mid] + 8LL * mid;
        if (f < target) lo = mid + 1; else hi = mid;
    }
    qlo[q] = lo & ~1;                                     // even-align for pairing
}

// bucketB: scatter EA to final split arrays. With dinv pre-scaled into the
// planes, norm reduces to the edge weight w -- no dinv gathers here.
__global__ __launch_bounds__(256) void bucketB_kernel(const int2* __restrict__ EA,
                                                      const int* __restrict__ bsumX,
                                                      const int* __restrict__ newbase,
                                                      unsigned int* __restrict__ srcoff,
                                                      half_t* __restrict__ normh) {
    __shared__ int cur[512];
    int b = blockIdx.x;
    int beg = bsumX[b];
    int end = (b == NBUCK - 1) ? N_EDGES : bsumX[b + 1];
    int i0 = threadIdx.x, i1 = threadIdx.x + 256;
    int col0 = (b << BSHIFT) + i0, col1 = (b << BSHIFT) + i1;
    cur[i0] = (col0 < N_NODES) ? newbase[col0] : 0;
    cur[i1] = (col1 < N_NODES) ? newbase[col1] : 0;
    __syncthreads();
    for (int e = beg + threadIdx.x; e < end; e += 256) {
        int2 ed = EA[e];
        int c = ed.y & 0x1ffff;
        float w = (float)((unsigned int)ed.y >> 17) * (1.0f / 8192.0f);
        int pos = atomicAdd(&cur[c & 511], 1);            // LDS atomic
        srcoff[pos] = (unsigned int)ed.x << 5;            // byte offset into plane
        normh[pos] = (half_t)w;
    }
}

// ---------------- layer-1 GEMM (K=14, VALU), dinv-scaled grouped store -------

template <int K>
__global__ __launch_bounds__(256) void gemm_kernel(const float* __restrict__ h,
                                                   const float* __restrict__ W,
                                                   const float* __restrict__ dinv,
                                                   half_t* __restrict__ xw, int n_nodes) {
    int f = threadIdx.x & 63;
    float wcol[K];
#pragma unroll
    for (int k = 0; k < K; k++) wcol[k] = W[k * HID + f];
    half_t* xg = xw + (size_t)(f >> 4) * GSTRIDE + (f & 15);
    int wave = (blockIdx.x * blockDim.x + threadIdx.x) >> 6;
    int nwaves = (gridDim.x * blockDim.x) >> 6;
    for (int n = wave; n < n_nodes; n += nwaves) {
        const float* hr = h + (size_t)n * K;
        float acc = 0.f;
#pragma unroll
        for (int k = 0; k < K; k++) acc += hr[k] * wcol[k];
        xg[(size_t)n * 16] = (half_t)(acc * dinv[n]);     // pre-scaled plane
    }
}

// ------- MFMA GEMM: fp16 h planes in, fused BN+ReLU, dinv-scaled store -------
__global__ __launch_bounds__(256) void gemm_bn_mfma_kernel(const half_t* __restrict__ h,
                                                           const float* __restrict__ W,
                                                           const float* __restrict__ stats,
                                                           const float* __restrict__ gamma,
                                                           const float* __restrict__ beta,
                                                           const float* __restrict__ dinv,
                                                           half_t* __restrict__ xw, int n_nodes) {
    __shared__ float sc_s[HID], sh_s[HID];
    if (threadIdx.x < 64) {
        float mean = stats[threadIdx.x] * (1.0f / N_NODES);
        float var = stats[64 + threadIdx.x] * (1.0f / N_NODES) - mean * mean;
        float sc = gamma[threadIdx.x] * rsqrtf(var + EPS);
        sc_s[threadIdx.x] = sc;
        sh_s[threadIdx.x] = beta[threadIdx.x] - mean * sc;
    }
    __syncthreads();
    int lane = threadIdx.x & 63;
    int col16 = lane & 15;
    int quad = lane >> 4;

    float scA[2][8], shA[2][8];
#pragma unroll
    for (int kh = 0; kh < 2; kh++)
#pragma unroll
        for (int j = 0; j < 8; j++) {
            int k = kh * 32 + quad * 8 + j;
            scA[kh][j] = sc_s[k];
            shA[kh][j] = sh_s[k];
        }

    half8 bfrag[4][2];
#pragma unroll
    for (int t = 0; t < 4; t++)
#pragma unroll
        for (int kh = 0; kh < 2; kh++)
#pragma unroll
            for (int j = 0; j < 8; j++) {
                int k = kh * 32 + quad * 8 + j;
                bfrag[t][kh][j] = (half_t)W[k * HID + t * 16 + col16];
            }

    int wave = (blockIdx.x * blockDim.x + threadIdx.x) >> 6;
    int nwaves = (gridDim.x * blockDim.x) >> 6;
    int ntiles = n_nodes >> 4;
    for (int tIdx = wave; tIdx < ntiles; tIdx += nwaves) {
        int n0 = tIdx << 4;
        half8 afrag[2];
#pragma unroll
        for (int kh = 0; kh < 2; kh++) {
            int k0 = kh * 32 + quad * 8;
            const half_t* hp = h + (size_t)(k0 >> 4) * GSTRIDE
                                 + (size_t)(n0 + col16) * 16 + (k0 & 15);
            half8 raw = *(const half8*)hp;
#pragma unroll
            for (int j = 0; j < 8; j++) {
                float v = (float)raw[j] * scA[kh][j] + shA[kh][j];
                afrag[kh][j] = (half_t)fmaxf(v, 0.f);
            }
        }
        f32x4 acc[4];
#pragma unroll
        for (int t = 0; t < 4; t++) {
            f32x4 z = {0.f, 0.f, 0.f, 0.f};
            acc[t] = __builtin_amdgcn_mfma_f32_16x16x32_f16(afrag[0], bfrag[t][0], z, 0, 0, 0);
            acc[t] = __builtin_amdgcn_mfma_f32_16x16x32_f16(afrag[1], bfrag[t][1], acc[t], 0, 0, 0);
        }
        f32x4 dv = *(const f32x4*)(dinv + n0 + quad * 4); // rows quad*4..+3
#pragma unroll
        for (int t = 0; t < 4; t++) {
            half_t* xg = xw + (size_t)t * GSTRIDE;
#pragma unroll
            for (int r = 0; r < 4; r++) {
                int rowi = n0 + quad * 4 + r;
                xg[(size_t)rowi * 16 + col16] = (half_t)(acc[t][r] * dv[r]);
            }
        }
    }
}

// ------- feature-grouped CSR gather: quad per NODE-PAIR, contiguous ranges ---
// r4's proven pair-interleaved shfl inner loop, with (a) edge-balanced
// CONTIGUOUS per-quad node ranges from qbounds (kills the 6-vs-7 iteration
// tail behind Occupancy=61%, streams metadata), (b) unmasked metadata loads
// (shfl bounds already guard; over-read stays in-allocation), (c) pre-scaled
// planes: norm==w, epilogue v = di*(acc+self') + b.
__global__ __launch_bounds__(256) void gather_stats_kernel(const int* __restrict__ ptrS,
                                                           const int* __restrict__ perm,
                                                           const unsigned int* __restrict__ srcoff,
                                                           const unsigned int* __restrict__ normu,
                                                           const half_t* __restrict__ xw,
                                                           const float* __restrict__ dinv,
                                                           const float* __restrict__ b,
                                                           half_t* __restrict__ hp,
                                                           float* __restrict__ stats,
                                                           const int* __restrict__ qlo,
                                                           int n_nodes) {
    int g = (blockIdx.x & 7) >> 1;                           // feature group 0..3
    int grank = ((blockIdx.x >> 3) << 1) | (blockIdx.x & 1); // rank within group
    int lane16 = threadIdx.x & 15;
    int quadLocal = threadIdx.x >> 4;                        // 0..15
    int quadId = grank * 16 + quadLocal;                     // 0..8191

    const half_t* xg = xw + (size_t)g * GSTRIDE;
    const char* xgc = (const char*)xg;
    unsigned int loff = (unsigned int)(lane16 * 2);
    half_t* hpg = hp + (size_t)g * GSTRIDE;
    float bf = b[g * 16 + lane16];
    int base = ((threadIdx.x & 63) >> 4) * 16;               // quad's shfl window

    float s = 0.f, s2 = 0.f;

    int lo = qlo[quadId], hi = qlo[quadId + 1];              // even-aligned range

    int i = lo;
    int nodeA = 0, begA = 0, cA = 0, nodeB = 0, begB = 0, cB = 0;
    int evA = 0, nvA = 0, evB = 0, nvB = 0;
    if (i < hi) {
        nodeA = perm[i];
        nodeB = perm[i + 1];
        begA = ptrS[i];
        begB = ptrS[i + 1];
        cA = begB - begA;
        cB = ptrS[i + 2] - begB;                             // >= cA (sorted)
        evA = (int)srcoff[begA + lane16];
        nvA = (int)normu[(begA >> 1) + lane16];
        evB = (int)srcoff[begB + lane16];
        nvB = (int)normu[(begB >> 1) + lane16];
    }

    while (i < hi) {
        int inext = i + 2;
        int nodeA2 = 0, begA2 = 0, cA2 = 0, nodeB2 = 0, begB2 = 0, cB2 = 0;
        if (inext < hi) {                                    // prefetch next headers
            nodeA2 = perm[inext];
            nodeB2 = perm[inext + 1];
            begA2 = ptrS[inext];
            begB2 = ptrS[inext + 1];
            cA2 = begB2 - begA2;
            cB2 = ptrS[inext + 2] - begB2;
        }
        float selfA = (float)xg[(size_t)nodeA * 16 + lane16];
        float diA = dinv[nodeA];
        float selfB = (float)xg[(size_t)nodeB * 16 + lane16];
        float diB = dinv[nodeB];

        __half2 aA0 = __float2half2_rn(0.f), aA1 = __float2half2_rn(0.f);
        __half2 aB0 = __float2half2_rn(0.f), aB1 = __float2half2_rn(0.f);

        for (int j0 = 0; j0 < cB; j0 += 16) {                // cB >= cA
            int mA = cA - j0; mA = (mA < 0) ? 0 : ((mA > 16) ? 16 : mA);
            int mB = cB - j0; mB = (mB > 16) ? 16 : mB;
            int pA = mA >> 1;                                // even (pad-4)
            int pB = mB >> 1;                                // even, >= pA
            int evA2 = 0, nvA2 = 0, evB2 = 0, nvB2 = 0;
            int j1 = j0 + 16;
            if (j1 < cA) {                                   // unmasked prefetch
                evA2 = (int)srcoff[begA + j1 + lane16];
                nvA2 = (int)normu[((begA + j1) >> 1) + lane16];
            }
            if (j1 < cB) {
                evB2 = (int)srcoff[begB + j1 + lane16];
                nvB2 = (int)normu[((begB + j1) >> 1) + lane16];
            }
            for (int p = 0; p < pB; p += 2) {
                // ---- node B, pairs p, p+1 (always full) ----
                unsigned int ub0 = (unsigned int)__shfl(evB, base + 2 * p);
                unsigned int ub1 = (unsigned int)__shfl(evB, base + 2 * p + 1);
                unsigned int ub2 = (unsigned int)__shfl(evB, base + 2 * p + 2);
                unsigned int ub3 = (unsigned int)__shfl(evB, base + 2 * p + 3);
                unsigned int nb0 = (unsigned int)__shfl(nvB, base + p);
                unsigned int nb1 = (unsigned int)__shfl(nvB, base + p + 1);
                __half hb0 = *(const __half*)(xgc + (ub0 + loff));
                __half hb1 = *(const __half*)(xgc + (ub1 + loff));
                __half hb2 = *(const __half*)(xgc + (ub2 + loff));
                __half hb3 = *(const __half*)(xgc + (ub3 + loff));
                aB0 = __hfma2(*(__half2*)&nb0, __halves2half2(hb0, hb1), aB0);
                aB1 = __hfma2(*(__half2*)&nb1, __halves2half2(hb2, hb3), aB1);
                // ---- node A, pairs p, p+1 (pA even => full when p < pA) ----
                if (p < pA) {
                    unsigned int ua0 = (unsigned int)__shfl(evA, base + 2 * p);
                    unsigned int ua1 = (unsigned int)__shfl(evA, base + 2 * p + 1);
                    unsigned int ua2 = (unsigned int)__shfl(evA, base + 2 * p + 2);
                    unsigned int ua3 = (unsigned int)__shfl(evA, base + 2 * p + 3);
                    unsigned int na0 = (unsigned int)__shfl(nvA, base + p);
                    unsigned int na1 = (unsigned int)__shfl(nvA, base + p + 1);
                    __half ha0 = *(const __half*)(xgc + (ua0 + loff));
                    __half ha1 = *(const __half*)(xgc + (ua1 + loff));
                    __half ha2 = *(const __half*)(xgc + (ua2 + loff));
                    __half ha3 = *(const __half*)(xgc + (ua3 + loff));
                    aA0 = __hfma2(*(__half2*)&na0, __halves2half2(ha0, ha1), aA0);
                    aA1 = __hfma2(*(__half2*)&na1, __halves2half2(ha2, ha3), aA1);
                }
            }
            evA = evA2; nvA = nvA2; evB = evB2; nvB = nvB2;
        }
        if (inext < hi) {                                    // prefetch next window-0
            evA = (int)srcoff[begA2 + lane16];
            nvA = (int)normu[(begA2 >> 1) + lane16];
            evB = (int)srcoff[begB2 + lane16];
            nvB = (int)normu[(begB2 >> 1) + lane16];
        }

        float accA = (__low2float(aA0) + __high2float(aA0))
                   + (__low2float(aA1) + __high2float(aA1));
        float vA = diA * (accA + selfA) + bf;                // pre-scaled algebra
        hpg[(size_t)nodeA * 16 + lane16] = (half_t)vA;
        float accB = (__low2float(aB0) + __high2float(aB0))
                   + (__low2float(aB1) + __high2float(aB1));
        float vB = diB * (accB + selfB) + bf;
        hpg[(size_t)nodeB * 16 + lane16] = (half_t)vB;
        s += vA + vB;
        s2 += vA * vA + vB * vB;

        i = inext;
        nodeA = nodeA2; begA = begA2; cA = cA2;
        nodeB = nodeB2; begB = begB2; cB = cB2;
    }
    __shared__ float ls[256], ls2[256];
    ls[threadIdx.x] = s;
    ls2[threadIdx.x] = s2;
    __syncthreads();
    if (threadIdx.x < 16) {
        float a = 0.f, aa = 0.f;
#pragma unroll
        for (int k = 0; k < 16; k++) {
            a += ls[k * 16 + threadIdx.x];
            aa += ls2[k * 16 + threadIdx.x];
        }
        atomicAdd(&stats[g * 16 + threadIdx.x], a);
        atomicAdd(&stats[64 + g * 16 + threadIdx.x], aa);
    }
}

// -------- layer 3: BN + ReLU from fp16 planes -> fp32 node_embs + segsum -----
__global__ __launch_bounds__(256) void bn_relu_seg_kernel(const half_t* __restrict__ hpl,
                                                          float* __restrict__ h3,
                                                          const float* __restrict__ stats,
                                                          const float* __restrict__ gamma,
                                                          const float* __restrict__ beta,
                                                          const int* __restrict__ batch,
                                                          float* __restrict__ gemb,
                                                          int n_nodes) {
    int g = blockIdx.x * blockDim.x + threadIdx.x;
    int f = g & 63;
    int wave = g >> 6;
    int nwaves = (gridDim.x * blockDim.x) >> 6;
    int chunk = (n_nodes + nwaves - 1) / nwaves;
    int n0 = wave * chunk;
    int n1 = n0 + chunk;
    if (n1 > n_nodes) n1 = n_nodes;
    if (n0 >= n_nodes) return;
    float mean = stats[f] * (1.0f / N_NODES);
    float var = stats[64 + f] * (1.0f / N_NODES) - mean * mean;
    float sc = gamma[f] * rsqrtf(var + EPS);
    float sh = beta[f] - mean * sc;
    const half_t* hg = hpl + (size_t)(f >> 4) * GSTRIDE + (f & 15);
    int curg = batch[n0];
    float racc = 0.f;
    for (int n = n0; n < n1; n++) {
        int bg = batch[n];
        if (bg != curg) {
            atomicAdd(&gemb[(size_t)curg * HID + f], racc);
            racc = 0.f;
            curg = bg;
        }
        float v = (float)hg[(size_t)n * 16] * sc + sh;
        v = fmaxf(v, 0.f);
        h3[(size_t)n * HID + f] = v;
        racc += v;
    }
    atomicAdd(&gemb[(size_t)curg * HID + f], racc);
}

__global__ __launch_bounds__(256) void final_kernel(const float* __restrict__ gemb,
                                                    const float* __restrict__ fcW,
                                                    const float* __restrict__ fcb,
                                                    float* __restrict__ out) {
    int g = blockIdx.x * blockDim.x + threadIdx.x;
    if (g >= N_GRAPHS * N_CLS) return;
    int gr = g >> 1, c = g & 1;
    float acc = fcb[c];
#pragma unroll
    for (int k = 0; k < HID; k++) acc += gemb[gr * HID + k] * fcW[k * N_CLS + c];
    out[g] = acc;
}

// ---------------- launch ----------------

extern "C" void kernel_launch(void* const* d_in, const int* in_sizes, int n_in,
                              void* d_out, int out_size, void* d_ws, size_t ws_size,
                              hipStream_t stream) {
    const float* x    = (const float*)d_in[0];
    const int*   ei   = (const int*)d_in[1];
    const int*   batch= (const int*)d_in[2];
    const float* ew   = (const float*)d_in[3];
    const float* W1   = (const float*)d_in[4];
    const float* b1   = (const float*)d_in[5];
    const float* W2   = (const float*)d_in[6];
    const float* b2   = (const float*)d_in[7];
    const float* W3   = (const float*)d_in[8];
    const float* b3   = (const float*)d_in[9];
    const float* g1   = (const float*)d_in[10];
    const float* bt1  = (const float*)d_in[11];
    const float* g2   = (const float*)d_in[12];
    const float* bt2  = (const float*)d_in[13];
    const float* g3   = (const float*)d_in[14];
    const float* bt3  = (const float*)d_in[15];
    const float* fcW  = (const float*)d_in[16];
    const float* fcb  = (const float*)d_in[17];

    const int* row = ei;
    const int* col = ei + N_EDGES;

    // d_out layout: out [2048*2] | node_embs [100000*64] | graph_emb [2048*64]
    float* out_head  = (float*)d_out;
    float* node_embs = out_head + N_GRAPHS * N_CLS;
    float* gemb      = node_embs + (size_t)N_NODES * HID;

    // ws layout with lifetime overlays:
    //  R0 (12.8 MB): xwh planes
    //  R1 (12.8 MB): EA (CSR build) -> h fp16 planes (written after EA dead)
    //  R2 (12.0 MB): srcoff u32[EMAX2] + normh f16[EMAX2]
    char* bse = (char*)d_ws;
    half_t* xwh = (half_t*)bse;                        // R0
    char* r1 = bse + (size_t)N_NODES * HID * 2;        // 12.8e6 (16-aligned)
    int2*   EA  = (int2*)r1;                           // R1
    half_t* hpl = (half_t*)r1;                         // h fp16 planes
    char* r2 = r1 + (size_t)N_NODES * HID * 2;
    unsigned int* srcoff = (unsigned int*)r2;          // EMAX2 u32
    half_t* normh = (half_t*)(srcoff + EMAX2);         // EMAX2 f16
    char* r3 = r2 + (size_t)EMAX2 * 6;
    float* dinv  = (float*)r3;                         // 400 KB
    float* stats3 = dinv + N_NODES;                    // 3 x 128 floats
    int*   ptr   = (int*)(stats3 + 384);               // (N+1) ints
    int*   histG = ptr + N_NODES + 1;                  // NBUCK*ABLOCKS
    int*   bsumA = histG + NBUCK * ABLOCKS;            // NBUCK (raw sums)
    int*   bsumX = bsumA + NBUCK + 4;                  // NBUCK (excl prefix)
    int*   histD = bsumX + NBUCK + 4;                  // 256*NBLK2
    int*   rowTot = histD + 256 * NBLK2;               // 256
    int*   nodeExcl = rowTot + 256;                    // 256
    int*   edgeExcl = nodeExcl + 256;                  // 256
    int*   perm   = edgeExcl + 256;                    // N
    int*   newbase= perm + N_NODES;                    // N
    int*   ptrS   = newbase + N_NODES;                 // N+1
    int*   qlo    = ptrS + N_NODES + 1;                // NQUADS+1

    const int B   = 256;
    const int gGS = 1024;   // grid-stride
    const int gGA = 2048;   // gather (mult of 8)

    // ---- CSR build: LDS counting sort, zero global atomics ----
    histA_kernel<<<ABLOCKS, B, 0, stream>>>(col, histG, gemb, stats3);
    scanS1_kernel<<<NBUCK, B, 0, stream>>>(histG, bsumA);
    scanS3_kernel<<<NBUCK, B, 0, stream>>>(histG, bsumA, bsumX, ptr);
    scatterA_kernel<<<ABLOCKS, B, 0, stream>>>(row, col, ew, histG, EA);
    bucketA_kernel<<<NBUCK, B, 0, stream>>>(EA, bsumX, ptr, dinv);

    // ---- degree sort of nodes (pad-4 edge layout) ----
    histD_kernel<<<NBLK2, B, 0, stream>>>(ptr, histD);
    scanD1_kernel<<<256, 128, 0, stream>>>(histD, rowTot);
    scanD3_kernel<<<256, 128, 0, stream>>>(histD, rowTot, nodeExcl, edgeExcl, ptrS);
    scatterD_kernel<<<NBLK2, B, 0, stream>>>(ptr, histD, nodeExcl, edgeExcl,
                                             perm, ptrS, newbase, srcoff, normh);
    qbounds_kernel<<<(NQUADS + 256) / 256, B, 0, stream>>>(ptrS, qlo);
    bucketB_kernel<<<NBUCK, B, 0, stream>>>(EA, bsumX, newbase, srcoff, normh);

    float* h3 = node_embs;  // fp32 post-BN output (written by bn_relu_seg)

    // ---- layer 1 ----
    gemm_kernel<IN_F><<<gGS, B, 0, stream>>>(x, W1, dinv, xwh, N_NODES);
    gather_stats_kernel<<<gGA, B, 0, stream>>>(ptrS, perm, srcoff,
                                               (const unsigned int*)normh, xwh,
                                               dinv, b1, hpl, stats3, qlo, N_NODES);

    // ---- layer 2 (BN1+ReLU fused into MFMA GEMM; fp16 h planes in) ----
    gemm_bn_mfma_kernel<<<gGS, B, 0, stream>>>(hpl, W2, stats3, g1, bt1, dinv, xwh, N_NODES);
    gather_stats_kernel<<<gGA, B, 0, stream>>>(ptrS, perm, srcoff,
                                               (const unsigned int*)normh, xwh,
                                               dinv, b2, hpl, stats3 + 128, qlo, N_NODES);

    // ---- layer 3 (BN2+ReLU fused into MFMA GEMM) ----
    gemm_bn_mfma_kernel<<<gGS, B, 0, stream>>>(hpl, W3, stats3 + 128, g2, bt2, dinv, xwh, N_NODES);
    gather_stats_kernel<<<gGA, B, 0, stream>>>(ptrS, perm, srcoff,
                                               (const unsigned int*)normh, xwh,
                                               dinv, b3, hpl, stats3 + 256, qlo, N_NODES);

    // ---- BN3 + ReLU (from fp16 planes) + node_embs + segment-sum ----
    bn_relu_seg_kernel<<<gGS, B, 0, stream>>>(hpl, h3, stats3 + 256, g3, bt3,
                                              batch, gemb, N_NODES);

    // ---- readout ----
    final_kernel<<<(N_GRAPHS * N_CLS + B - 1) / B, B, 0, stream>>>(gemb, fcW, fcb, out_head);
}

// Round 6
// 395.805 us; speedup vs baseline: 1.1513x; 1.1513x over previous
//
#include <hip/hip_runtime.h>
#include <hip/hip_fp16.h>

#define N_NODES 100000
#define N_EDGES 1600000
#define EMAX2   2000000                 // pad-4 edge capacity (1.6M + <=3*100K)
#define N_GRAPHS 2048
#define HID 64
#define IN_F 14
#define N_CLS 2
#define EPS 1e-5f

#define BSHIFT 9
#define NBUCK 196                       // ceil(100000 / 512)
#define ABLOCKS 256
#define CHUNK (N_EDGES / ABLOCKS)       // 6250, exact

#define NBLK2 128                       // node-sort blocks
#define NCHUNK2 ((N_NODES + NBLK2 - 1) / NBLK2)  // 782

typedef _Float16 half_t;
typedef _Float16 half8 __attribute__((ext_vector_type(8)));
typedef float f32x4 __attribute__((ext_vector_type(4)));

#define GSTRIDE ((size_t)N_NODES * 16)  // halves per feature-group plane

// ============ CSR build, atomic-free (global) two-level counting sort ========

// histA + fold-in: zero gemb (atomic target of bn_relu_seg) and stats3.
__global__ __launch_bounds__(256) void histA_kernel(const int* __restrict__ col,
                                                    int* __restrict__ histG,
                                                    float* __restrict__ gemb,
                                                    float* __restrict__ stats3) {
    __shared__ int hl[NBUCK];
    for (int i = threadIdx.x; i < NBUCK; i += 256) hl[i] = 0;
    // zero gemb: 256 blocks x 512 floats = 2048*64
    for (int k = threadIdx.x; k < 512; k += 256)
        gemb[(size_t)blockIdx.x * 512 + k] = 0.f;
    if (blockIdx.x == 0 && threadIdx.x < 384) stats3[threadIdx.x] = 0.f;
    __syncthreads();
    int e0 = blockIdx.x * CHUNK;
    for (int e = e0 + threadIdx.x; e < e0 + CHUNK; e += 256)
        atomicAdd(&hl[col[e] >> BSHIFT], 1);
    __syncthreads();
    for (int i = threadIdx.x; i < NBUCK; i += 256)
        histG[i * ABLOCKS + blockIdx.x] = hl[i];
}

__global__ __launch_bounds__(256) void scanS1_kernel(const int* __restrict__ histG,
                                                     int* __restrict__ bsumA) {
    __shared__ int ls[256];
    ls[threadIdx.x] = histG[blockIdx.x * 256 + threadIdx.x];
    __syncthreads();
    for (int off = 128; off > 0; off >>= 1) {
        if (threadIdx.x < off) ls[threadIdx.x] += ls[threadIdx.x + off];
        __syncthreads();
    }
    if (threadIdx.x == 0) bsumA[blockIdx.x] = ls[0];
}

// scanS3 with fused bucket-level prefix (topscan merged): every block scans
// bsumA (raw sums) in LDS; bsumX gets the exclusive bucket prefix.
__global__ __launch_bounds__(256) void scanS3_kernel(int* __restrict__ histG,
                                                     const int* __restrict__ bsumA,
                                                     int* __restrict__ bsumX,
                                                     int* __restrict__ ptr) {
    __shared__ int ls[256], bs[256];
    int t = threadIdx.x;
    int rawB = (blockIdx.x < NBUCK) ? bsumA[blockIdx.x] : 0;
    bs[t] = (t < NBUCK) ? bsumA[t] : 0;
    int idx = blockIdx.x * 256 + t;
    int v = histG[idx];
    ls[t] = v;
    __syncthreads();
    for (int off = 1; off < 256; off <<= 1) {
        int x = ls[t];
        int y = bs[t];
        if (t >= off) { x += ls[t - off]; y += bs[t - off]; }
        __syncthreads();
        ls[t] = x; bs[t] = y;
        __syncthreads();
    }
    int bexcl = bs[blockIdx.x] - rawB;            // exclusive bucket prefix
    histG[idx] = ls[t] - v + bexcl;
    if (t == 0) bsumX[blockIdx.x] = bexcl;
    if (blockIdx.x == 0 && t == 0) ptr[N_NODES] = N_EDGES;
}

__global__ __launch_bounds__(256) void scatterA_kernel(const int* __restrict__ row,
                                                       const int* __restrict__ col,
                                                       const float* __restrict__ w,
                                                       const int* __restrict__ histG,
                                                       int2* __restrict__ EA) {
    __shared__ int cur[NBUCK];
    for (int i = threadIdx.x; i < NBUCK; i += 256)
        cur[i] = histG[i * ABLOCKS + blockIdx.x];
    __syncthreads();
    int e0 = blockIdx.x * CHUNK;
    for (int e = e0 + threadIdx.x; e < e0 + CHUNK; e += 256) {
        int c = col[e];
        int r = row[e];
        int fx = (int)__float2uint_rn(w[e] * 8192.0f);   // 15-bit fixed, exact for w=1
        int pos = atomicAdd(&cur[c >> BSHIFT], 1);        // LDS atomic
        EA[pos] = make_int2(r, (fx << 17) | c);
    }
}

// bucketA: per-bucket dense hist+scan -> ptr (unpadded CSR base), dinv
__global__ __launch_bounds__(256) void bucketA_kernel(const int2* __restrict__ EA,
                                                      const int* __restrict__ bsumX,
                                                      int* __restrict__ ptr,
                                                      float* __restrict__ dinv) {
    __shared__ int hist[512], wsum[512];
    int b = blockIdx.x;
    int beg = bsumX[b];
    int end = (b == NBUCK - 1) ? N_EDGES : bsumX[b + 1];
    int i0 = threadIdx.x, i1 = threadIdx.x + 256;
    hist[i0] = 0; hist[i1] = 0;
    wsum[i0] = 0; wsum[i1] = 0;
    __syncthreads();
    for (int e = beg + threadIdx.x; e < end; e += 256) {
        int2 ed = EA[e];
        int c9 = ed.y & 511;
        atomicAdd(&hist[c9], 1);
        atomicAdd(&wsum[c9], (int)((unsigned int)ed.y >> 17));
    }
    __syncthreads();
    int cnt0 = hist[i0], cnt1 = hist[i1];
    for (int off = 1; off < 512; off <<= 1) {
        int v0 = hist[i0], v1 = hist[i1];
        int a0 = (i0 >= off) ? hist[i0 - off] : 0;
        int a1 = (i1 >= off) ? hist[i1 - off] : 0;
        __syncthreads();
        hist[i0] = v0 + a0;
        hist[i1] = v1 + a1;
        __syncthreads();
    }
    int excl0 = hist[i0] - cnt0, excl1 = hist[i1] - cnt1;
    int col0 = (b << BSHIFT) + i0, col1 = (b << BSHIFT) + i1;
    if (col0 < N_NODES) {
        ptr[col0] = beg + excl0;
        dinv[col0] = rsqrtf(1.0f + (float)wsum[i0] * (1.0f / 8192.0f));
    }
    if (col1 < N_NODES) {
        ptr[col1] = beg + excl1;
        dinv[col1] = rsqrtf(1.0f + (float)wsum[i1] * (1.0f / 8192.0f));
    }
}

// ============ node degree sort (pad-4 edge layout) ===========================

__global__ __launch_bounds__(256) void histD_kernel(const int* __restrict__ ptr,
                                                    int* __restrict__ histD) {
    __shared__ int hl[2048];
    for (int i = threadIdx.x; i < 2048; i += 256) hl[i] = 0;
    __syncthreads();
    int n0 = blockIdx.x * NCHUNK2;
    int n1 = n0 + NCHUNK2; if (n1 > N_NODES) n1 = N_NODES;
    for (int n = n0 + threadIdx.x; n < n1; n += 256) {
        int d = ptr[n + 1] - ptr[n];
        if (d > 255) d = 255;
        atomicAdd(&hl[((threadIdx.x & 7) << 8) + d], 1);
    }
    __syncthreads();
    int s = 0;
#pragma unroll
    for (int c = 0; c < 8; c++) s += hl[(c << 8) + threadIdx.x];
    histD[threadIdx.x * NBLK2 + blockIdx.x] = s;
}

__global__ __launch_bounds__(128) void scanD1_kernel(const int* __restrict__ histD,
                                                     int* __restrict__ rowTot) {
    __shared__ int ls[128];
    ls[threadIdx.x] = histD[blockIdx.x * NBLK2 + threadIdx.x];
    __syncthreads();
    for (int off = 64; off > 0; off >>= 1) {
        if (threadIdx.x < off) ls[threadIdx.x] += ls[threadIdx.x + off];
        __syncthreads();
    }
    if (threadIdx.x == 0) rowTot[blockIdx.x] = ls[0];
}

// scanD3 with fused bin-level dual prefix (topscanD merged): every block
// (one per bin) scans rowTot in LDS for node counts + pad-4 edge counts;
// block 0 publishes nodeExcl/edgeExcl/ptrS[N] for scatterD.
__global__ __launch_bounds__(128) void scanD3_kernel(int* __restrict__ histD,
                                                     const int* __restrict__ rowTot,
                                                     int* __restrict__ nodeExcl,
                                                     int* __restrict__ edgeExcl,
                                                     int* __restrict__ ptrS) {
    __shared__ int ls[128], sa[256], sb[256];
    int t = threadIdx.x;
    int bin = blockIdx.x;
    int c0 = rowTot[t], c1 = rowTot[t + 128];
    sa[t] = c0;           sa[t + 128] = c1;
    sb[t] = c0 * ((t + 3) & ~3);
    sb[t + 128] = c1 * ((t + 131) & ~3);
    int idx = bin * NBLK2 + t;
    int v = histD[idx];
    ls[t] = v;
    __syncthreads();
    for (int off = 1; off < 256; off <<= 1) {     // 256-wide dual scan, 2/thread
        int a0 = sa[t], a1 = sa[t + 128];
        int b0 = sb[t], b1 = sb[t + 128];
        int x0 = (t >= off) ? sa[t - off] : 0;
        int x1 = (t + 128 >= off) ? sa[t + 128 - off] : 0;
        int y0 = (t >= off) ? sb[t - off] : 0;
        int y1 = (t + 128 >= off) ? sb[t + 128 - off] : 0;
        __syncthreads();
        sa[t] = a0 + x0; sa[t + 128] = a1 + x1;
        sb[t] = b0 + y0; sb[t + 128] = b1 + y1;
        __syncthreads();
    }
    for (int off = 1; off < 128; off <<= 1) {     // 128-wide histD column scan
        int x = ls[t];
        if (t >= off) x += ls[t - off];
        __syncthreads();
        ls[t] = x;
        __syncthreads();
    }
    int nE = sa[bin] - rowTot[bin];               // node-exclusive for this bin
    histD[idx] = ls[t] - v + nE;
    if (bin == 0) {
        nodeExcl[t] = sa[t] - rowTot[t];
        nodeExcl[t + 128] = sa[t + 128] - rowTot[t + 128];
        edgeExcl[t] = sb[t] - rowTot[t] * ((t + 3) & ~3);
        edgeExcl[t + 128] = sb[t + 128] - rowTot[t + 128] * ((t + 131) & ~3);
        if (t == 127) ptrS[N_NODES] = sb[255];    // total padded edges
    }
}

// scatterD + fold-in: zero the pad slots (srcoff/normh) so the big memset
// is unnecessary (only d..dpad-1 per node are pads; <=3 each).
__global__ __launch_bounds__(256) void scatterD_kernel(const int* __restrict__ ptr,
                                                       const int* __restrict__ histD,
                                                       const int* __restrict__ nodeExcl,
                                                       const int* __restrict__ edgeExcl,
                                                       int* __restrict__ perm,
                                                       int* __restrict__ ptrS,
                                                       int* __restrict__ newbase,
                                                       unsigned int* __restrict__ srcoff,
                                                       half_t* __restrict__ normh) {
    __shared__ int cur[256];
    cur[threadIdx.x] = histD[threadIdx.x * NBLK2 + blockIdx.x];
    __syncthreads();
    int n0 = blockIdx.x * NCHUNK2;
    int n1 = n0 + NCHUNK2; if (n1 > N_NODES) n1 = N_NODES;
    for (int n = n0 + threadIdx.x; n < n1; n += 256) {
        int d = ptr[n + 1] - ptr[n];
        if (d > 255) d = 255;
        int dpad = (d + 3) & ~3;
        int pos = atomicAdd(&cur[d], 1);                  // LDS atomic
        int ebase = edgeExcl[d] + (pos - nodeExcl[d]) * dpad;
        perm[pos] = n;
        ptrS[pos] = ebase;
        newbase[n] = ebase;
        for (int k = d; k < dpad; k++) {                  // zero pad slots
            srcoff[ebase + k] = 0u;
            normh[ebase + k] = (half_t)0.f;
        }
    }
}

// bucketB: scatter EA to final split arrays. With dinv pre-scaled into the
// planes, norm reduces to the edge weight w -- no dinv gathers here.
__global__ __launch_bounds__(256) void bucketB_kernel(const int2* __restrict__ EA,
                                                      const int* __restrict__ bsumX,
                                                      const int* __restrict__ newbase,
                                                      unsigned int* __restrict__ srcoff,
                                                      half_t* __restrict__ normh) {
    __shared__ int cur[512];
    int b = blockIdx.x;
    int beg = bsumX[b];
    int end = (b == NBUCK - 1) ? N_EDGES : bsumX[b + 1];
    int i0 = threadIdx.x, i1 = threadIdx.x + 256;
    int col0 = (b << BSHIFT) + i0, col1 = (b << BSHIFT) + i1;
    cur[i0] = (col0 < N_NODES) ? newbase[col0] : 0;
    cur[i1] = (col1 < N_NODES) ? newbase[col1] : 0;
    __syncthreads();
    for (int e = beg + threadIdx.x; e < end; e += 256) {
        int2 ed = EA[e];
        int c = ed.y & 0x1ffff;
        float w = (float)((unsigned int)ed.y >> 17) * (1.0f / 8192.0f);
        int pos = atomicAdd(&cur[c & 511], 1);            // LDS atomic
        srcoff[pos] = (unsigned int)ed.x << 5;            // byte offset into plane
        normh[pos] = (half_t)w;
    }
}

// ---------------- layer-1 GEMM (K=14, VALU), dinv-scaled grouped store -------

template <int K>
__global__ __launch_bounds__(256) void gemm_kernel(const float* __restrict__ h,
                                                   const float* __restrict__ W,
                                                   const float* __restrict__ dinv,
                                                   half_t* __restrict__ xw, int n_nodes) {
    int f = threadIdx.x & 63;
    float wcol[K];
#pragma unroll
    for (int k = 0; k < K; k++) wcol[k] = W[k * HID + f];
    half_t* xg = xw + (size_t)(f >> 4) * GSTRIDE + (f & 15);
    int wave = (blockIdx.x * blockDim.x + threadIdx.x) >> 6;
    int nwaves = (gridDim.x * blockDim.x) >> 6;
    for (int n = wave; n < n_nodes; n += nwaves) {
        const float* hr = h + (size_t)n * K;
        float acc = 0.f;
#pragma unroll
        for (int k = 0; k < K; k++) acc += hr[k] * wcol[k];
        xg[(size_t)n * 16] = (half_t)(acc * dinv[n]);     // pre-scaled plane
    }
}

// ------- MFMA GEMM: fp16 h planes in, fused BN+ReLU, dinv-scaled store -------
__global__ __launch_bounds__(256) void gemm_bn_mfma_kernel(const half_t* __restrict__ h,
                                                           const float* __restrict__ W,
                                                           const float* __restrict__ stats,
                                                           const float* __restrict__ gamma,
                                                           const float* __restrict__ beta,
                                                           const float* __restrict__ dinv,
                                                           half_t* __restrict__ xw, int n_nodes) {
    __shared__ float sc_s[HID], sh_s[HID];
    if (threadIdx.x < 64) {
        float mean = stats[threadIdx.x] * (1.0f / N_NODES);
        float var = stats[64 + threadIdx.x] * (1.0f / N_NODES) - mean * mean;
        float sc = gamma[threadIdx.x] * rsqrtf(var + EPS);
        sc_s[threadIdx.x] = sc;
        sh_s[threadIdx.x] = beta[threadIdx.x] - mean * sc;
    }
    __syncthreads();
    int lane = threadIdx.x & 63;
    int col16 = lane & 15;
    int quad = lane >> 4;

    float scA[2][8], shA[2][8];
#pragma unroll
    for (int kh = 0; kh < 2; kh++)
#pragma unroll
        for (int j = 0; j < 8; j++) {
            int k = kh * 32 + quad * 8 + j;
            scA[kh][j] = sc_s[k];
            shA[kh][j] = sh_s[k];
        }

    half8 bfrag[4][2];
#pragma unroll
    for (int t = 0; t < 4; t++)
#pragma unroll
        for (int kh = 0; kh < 2; kh++)
#pragma unroll
            for (int j = 0; j < 8; j++) {
                int k = kh * 32 + quad * 8 + j;
                bfrag[t][kh][j] = (half_t)W[k * HID + t * 16 + col16];
            }

    int wave = (blockIdx.x * blockDim.x + threadIdx.x) >> 6;
    int nwaves = (gridDim.x * blockDim.x) >> 6;
    int ntiles = n_nodes >> 4;
    for (int tIdx = wave; tIdx < ntiles; tIdx += nwaves) {
        int n0 = tIdx << 4;
        half8 afrag[2];
#pragma unroll
        for (int kh = 0; kh < 2; kh++) {
            int k0 = kh * 32 + quad * 8;
            const half_t* hp = h + (size_t)(k0 >> 4) * GSTRIDE
                                 + (size_t)(n0 + col16) * 16 + (k0 & 15);
            half8 raw = *(const half8*)hp;
#pragma unroll
            for (int j = 0; j < 8; j++) {
                float v = (float)raw[j] * scA[kh][j] + shA[kh][j];
                afrag[kh][j] = (half_t)fmaxf(v, 0.f);
            }
        }
        f32x4 acc[4];
#pragma unroll
        for (int t = 0; t < 4; t++) {
            f32x4 z = {0.f, 0.f, 0.f, 0.f};
            acc[t] = __builtin_amdgcn_mfma_f32_16x16x32_f16(afrag[0], bfrag[t][0], z, 0, 0, 0);
            acc[t] = __builtin_amdgcn_mfma_f32_16x16x32_f16(afrag[1], bfrag[t][1], acc[t], 0, 0, 0);
        }
        f32x4 dv = *(const f32x4*)(dinv + n0 + quad * 4); // rows quad*4..+3
#pragma unroll
        for (int t = 0; t < 4; t++) {
            half_t* xg = xw + (size_t)t * GSTRIDE;
#pragma unroll
            for (int r = 0; r < 4; r++) {
                int rowi = n0 + quad * 4 + r;
                xg[(size_t)rowi * 16 + col16] = (half_t)(acc[t][r] * dv[r]);
            }
        }
    }
}

// ------- feature-grouped CSR gather: quad per NODE-PAIR, paired fp16 math ----
// r4's proven structure: STRIDED pair walk (i += nquads) so the 4 quads of a
// wave read ADJACENT pairs' metadata -> one contiguous burst per wave (the
// r5 contiguous-range variant doubled FETCH_SIZE 74->145 MB; protect this).
// Masked metadata loads; edge metadata on VMEM once/window, broadcast on the
// DS pipe (independent lgkmcnt) so gathers overlap across windows. Pair
// interleave doubles chains/wave. Pre-scaled planes: norm==w, epilogue
// v = di*(acc+self') + b.
__global__ __launch_bounds__(256) void gather_stats_kernel(const int* __restrict__ ptrS,
                                                           const int* __restrict__ perm,
                                                           const unsigned int* __restrict__ srcoff,
                                                           const unsigned int* __restrict__ normu,
                                                           const half_t* __restrict__ xw,
                                                           const float* __restrict__ dinv,
                                                           const float* __restrict__ b,
                                                           half_t* __restrict__ hp,
                                                           float* __restrict__ stats,
                                                           int n_nodes) {
    int g = (blockIdx.x & 7) >> 1;                           // feature group 0..3
    int grank = ((blockIdx.x >> 3) << 1) | (blockIdx.x & 1); // rank within group
    int lane16 = threadIdx.x & 15;
    int quadLocal = threadIdx.x >> 4;                        // 0..15
    int quadId = grank * 16 + quadLocal;
    int nquads = (gridDim.x >> 2) * 16;

    const half_t* xg = xw + (size_t)g * GSTRIDE;
    const char* xgc = (const char*)xg;
    unsigned int loff = (unsigned int)(lane16 * 2);
    half_t* hpg = hp + (size_t)g * GSTRIDE;
    float bf = b[g * 16 + lane16];
    int base = ((threadIdx.x & 63) >> 4) * 16;               // quad's shfl window

    float s = 0.f, s2 = 0.f;

    int npairs = n_nodes >> 1;                               // N_NODES even
    int idx = quadId;
    int nodeA = 0, begA = 0, cA = 0, nodeB = 0, begB = 0, cB = 0;
    int evA = 0, nvA = 0, evB = 0, nvB = 0;
    if (idx < npairs) {
        int iA = idx * 2;
        nodeA = perm[iA];
        nodeB = perm[iA + 1];
        begA = ptrS[iA];
        begB = ptrS[iA + 1];
        cA = begB - begA;                                    // pad-4 degree of A
        cB = ptrS[iA + 2] - begB;                            // pad-4 degree of B (>= cA)
        int mA = (cA > 16) ? 16 : cA;
        int mB = (cB > 16) ? 16 : cB;
        if (lane16 < mA) evA = (int)srcoff[begA + lane16];
        if (lane16 < (mA >> 1)) nvA = (int)normu[(begA >> 1) + lane16];
        if (lane16 < mB) evB = (int)srcoff[begB + lane16];
        if (lane16 < (mB >> 1)) nvB = (int)normu[(begB >> 1) + lane16];
    }

    while (idx < npairs) {
        // prefetch next pair's headers
        int inext = idx + nquads;
        int nodeA2 = 0, begA2 = 0, cA2 = 0, nodeB2 = 0, begB2 = 0, cB2 = 0;
        if (inext < npairs) {
            int iN = inext * 2;
            nodeA2 = perm[iN];
            nodeB2 = perm[iN + 1];
            begA2 = ptrS[iN];
            begB2 = ptrS[iN + 1];
            cA2 = begB2 - begA2;
            cB2 = ptrS[iN + 2] - begB2;
        }
        // hoist self-loop values + dinv
        float selfA = (float)xg[(size_t)nodeA * 16 + lane16];
        float diA = dinv[nodeA];
        float selfB = (float)xg[(size_t)nodeB * 16 + lane16];
        float diB = dinv[nodeB];

        __half2 aA0 = __float2half2_rn(0.f), aA1 = __float2half2_rn(0.f);
        __half2 aB0 = __float2half2_rn(0.f), aB1 = __float2half2_rn(0.f);

        for (int j0 = 0; j0 < cB; j0 += 16) {                // cB >= cA
            int mA = cA - j0; mA = (mA < 0) ? 0 : ((mA > 16) ? 16 : mA);
            int mB = cB - j0; mB = (mB > 16) ? 16 : mB;
            int pA = mA >> 1;                                // even (pad-4)
            int pB = mB >> 1;                                // even, >= pA
            // prefetch next window for both nodes (masked)
            int evA2 = 0, nvA2 = 0, evB2 = 0, nvB2 = 0;
            int j1 = j0 + 16;
            if (j1 < cA) {
                int m2 = cA - j1; if (m2 > 16) m2 = 16;
                if (lane16 < m2) evA2 = (int)srcoff[begA + j1 + lane16];
                if (lane16 < (m2 >> 1)) nvA2 = (int)normu[((begA + j1) >> 1) + lane16];
            }
            if (j1 < cB) {
                int m2 = cB - j1; if (m2 > 16) m2 = 16;
                if (lane16 < m2) evB2 = (int)srcoff[begB + j1 + lane16];
                if (lane16 < (m2 >> 1)) nvB2 = (int)normu[((begB + j1) >> 1) + lane16];
            }
            for (int p = 0; p < pB; p += 2) {
                // ---- node B, pairs p, p+1 (always full) ----
                unsigned int ub0 = (unsigned int)__shfl(evB, base + 2 * p);
                unsigned int ub1 = (unsigned int)__shfl(evB, base + 2 * p + 1);
                unsigned int ub2 = (unsigned int)__shfl(evB, base + 2 * p + 2);
                unsigned int ub3 = (unsigned int)__shfl(evB, base + 2 * p + 3);
                unsigned int nb0 = (unsigned int)__shfl(nvB, base + p);
                unsigned int nb1 = (unsigned int)__shfl(nvB, base + p + 1);
                __half hb0 = *(const __half*)(xgc + (ub0 + loff));
                __half hb1 = *(const __half*)(xgc + (ub1 + loff));
                __half hb2 = *(const __half*)(xgc + (ub2 + loff));
                __half hb3 = *(const __half*)(xgc + (ub3 + loff));
                aB0 = __hfma2(*(__half2*)&nb0, __halves2half2(hb0, hb1), aB0);
                aB1 = __hfma2(*(__half2*)&nb1, __halves2half2(hb2, hb3), aB1);
                // ---- node A, pairs p, p+1 (pA even => full when p < pA) ----
                if (p < pA) {
                    unsigned int ua0 = (unsigned int)__shfl(evA, base + 2 * p);
                    unsigned int ua1 = (unsigned int)__shfl(evA, base + 2 * p + 1);
                    unsigned int ua2 = (unsigned int)__shfl(evA, base + 2 * p + 2);
                    unsigned int ua3 = (unsigned int)__shfl(evA, base + 2 * p + 3);
                    unsigned int na0 = (unsigned int)__shfl(nvA, base + p);
                    unsigned int na1 = (unsigned int)__shfl(nvA, base + p + 1);
                    __half ha0 = *(const __half*)(xgc + (ua0 + loff));
                    __half ha1 = *(const __half*)(xgc + (ua1 + loff));
                    __half ha2 = *(const __half*)(xgc + (ua2 + loff));
                    __half ha3 = *(const __half*)(xgc + (ua3 + loff));
                    aA0 = __hfma2(*(__half2*)&na0, __halves2half2(ha0, ha1), aA0);
                    aA1 = __hfma2(*(__half2*)&na1, __halves2half2(ha2, ha3), aA1);
                }
            }
            evA = evA2; nvA = nvA2; evB = evB2; nvB = nvB2;
        }
        // prefetch window-0 of the NEXT pair before the epilogue math
        if (inext < npairs) {
            int mA0 = (cA2 > 16) ? 16 : cA2;
            int mB0 = (cB2 > 16) ? 16 : cB2;
            evA = (lane16 < mA0) ? (int)srcoff[begA2 + lane16] : 0;
            nvA = (lane16 < (mA0 >> 1)) ? (int)normu[(begA2 >> 1) + lane16] : 0;
            evB = (lane16 < mB0) ? (int)srcoff[begB2 + lane16] : 0;
            nvB = (lane16 < (mB0 >> 1)) ? (int)normu[(begB2 >> 1) + lane16] : 0;
        }

        float accA = (__low2float(aA0) + __high2float(aA0))
                   + (__low2float(aA1) + __high2float(aA1));
        float vA = diA * (accA + selfA) + bf;                // pre-scaled algebra
        hpg[(size_t)nodeA * 16 + lane16] = (half_t)vA;
        float accB = (__low2float(aB0) + __high2float(aB0))
                   + (__low2float(aB1) + __high2float(aB1));
        float vB = diB * (accB + selfB) + bf;
        hpg[(size_t)nodeB * 16 + lane16] = (half_t)vB;
        s += vA + vB;
        s2 += vA * vA + vB * vB;

        idx = inext;
        nodeA = nodeA2; begA = begA2; cA = cA2;
        nodeB = nodeB2; begB = begB2; cB = cB2;
    }
    __shared__ float ls[256], ls2[256];
    ls[threadIdx.x] = s;
    ls2[threadIdx.x] = s2;
    __syncthreads();
    if (threadIdx.x < 16) {
        float a = 0.f, aa = 0.f;
#pragma unroll
        for (int k = 0; k < 16; k++) {
            a += ls[k * 16 + threadIdx.x];
            aa += ls2[k * 16 + threadIdx.x];
        }
        atomicAdd(&stats[g * 16 + threadIdx.x], a);
        atomicAdd(&stats[64 + g * 16 + threadIdx.x], aa);
    }
}

// -------- layer 3: BN + ReLU from fp16 planes -> fp32 node_embs + segsum -----
__global__ __launch_bounds__(256) void bn_relu_seg_kernel(const half_t* __restrict__ hpl,
                                                          float* __restrict__ h3,
                                                          const float* __restrict__ stats,
                                                          const float* __restrict__ gamma,
                                                          const float* __restrict__ beta,
                                                          const int* __restrict__ batch,
                                                          float* __restrict__ gemb,
                                                          int n_nodes) {
    int g = blockIdx.x * blockDim.x + threadIdx.x;
    int f = g & 63;
    int wave = g >> 6;
    int nwaves = (gridDim.x * blockDim.x) >> 6;
    int chunk = (n_nodes + nwaves - 1) / nwaves;
    int n0 = wave * chunk;
    int n1 = n0 + chunk;
    if (n1 > n_nodes) n1 = n_nodes;
    if (n0 >= n_nodes) return;
    float mean = stats[f] * (1.0f / N_NODES);
    float var = stats[64 + f] * (1.0f / N_NODES) - mean * mean;
    float sc = gamma[f] * rsqrtf(var + EPS);
    float sh = beta[f] - mean * sc;
    const half_t* hg = hpl + (size_t)(f >> 4) * GSTRIDE + (f & 15);
    int curg = batch[n0];
    float racc = 0.f;
    for (int n = n0; n < n1; n++) {
        int bg = batch[n];
        if (bg != curg) {
            atomicAdd(&gemb[(size_t)curg * HID + f], racc);
            racc = 0.f;
            curg = bg;
        }
        float v = (float)hg[(size_t)n * 16] * sc + sh;
        v = fmaxf(v, 0.f);
        h3[(size_t)n * HID + f] = v;
        racc += v;
    }
    atomicAdd(&gemb[(size_t)curg * HID + f], racc);
}

__global__ __launch_bounds__(256) void final_kernel(const float* __restrict__ gemb,
                                                    const float* __restrict__ fcW,
                                                    const float* __restrict__ fcb,
                                                    float* __restrict__ out) {
    int g = blockIdx.x * blockDim.x + threadIdx.x;
    if (g >= N_GRAPHS * N_CLS) return;
    int gr = g >> 1, c = g & 1;
    float acc = fcb[c];
#pragma unroll
    for (int k = 0; k < HID; k++) acc += gemb[gr * HID + k] * fcW[k * N_CLS + c];
    out[g] = acc;
}

// ---------------- launch ----------------

extern "C" void kernel_launch(void* const* d_in, const int* in_sizes, int n_in,
                              void* d_out, int out_size, void* d_ws, size_t ws_size,
                              hipStream_t stream) {
    const float* x    = (const float*)d_in[0];
    const int*   ei   = (const int*)d_in[1];
    const int*   batch= (const int*)d_in[2];
    const float* ew   = (const float*)d_in[3];
    const float* W1   = (const float*)d_in[4];
    const float* b1   = (const float*)d_in[5];
    const float* W2   = (const float*)d_in[6];
    const float* b2   = (const float*)d_in[7];
    const float* W3   = (const float*)d_in[8];
    const float* b3   = (const float*)d_in[9];
    const float* g1   = (const float*)d_in[10];
    const float* bt1  = (const float*)d_in[11];
    const float* g2   = (const float*)d_in[12];
    const float* bt2  = (const float*)d_in[13];
    const float* g3   = (const float*)d_in[14];
    const float* bt3  = (const float*)d_in[15];
    const float* fcW  = (const float*)d_in[16];
    const float* fcb  = (const float*)d_in[17];

    const int* row = ei;
    const int* col = ei + N_EDGES;

    // d_out layout: out [2048*2] | node_embs [100000*64] | graph_emb [2048*64]
    float* out_head  = (float*)d_out;
    float* node_embs = out_head + N_GRAPHS * N_CLS;
    float* gemb      = node_embs + (size_t)N_NODES * HID;

    // ws layout with lifetime overlays:
    //  R0 (12.8 MB): xwh planes
    //  R1 (12.8 MB): EA (CSR build) -> h fp16 planes (written after EA dead)
    //  R2 (12.0 MB): srcoff u32[EMAX2] + normh f16[EMAX2]
    char* bse = (char*)d_ws;
    half_t* xwh = (half_t*)bse;                        // R0
    char* r1 = bse + (size_t)N_NODES * HID * 2;        // 12.8e6 (16-aligned)
    int2*   EA  = (int2*)r1;                           // R1
    half_t* hpl = (half_t*)r1;                         // h fp16 planes
    char* r2 = r1 + (size_t)N_NODES * HID * 2;
    unsigned int* srcoff = (unsigned int*)r2;          // EMAX2 u32
    half_t* normh = (half_t*)(srcoff + EMAX2);         // EMAX2 f16
    char* r3 = r2 + (size_t)EMAX2 * 6;
    float* dinv  = (float*)r3;                         // 400 KB
    float* stats3 = dinv + N_NODES;                    // 3 x 128 floats
    int*   ptr   = (int*)(stats3 + 384);               // (N+1) ints
    int*   histG = ptr + N_NODES + 1;                  // NBUCK*ABLOCKS
    int*   bsumA = histG + NBUCK * ABLOCKS;            // NBUCK (raw sums)
    int*   bsumX = bsumA + NBUCK + 4;                  // NBUCK (excl prefix)
    int*   histD = bsumX + NBUCK + 4;                  // 256*NBLK2
    int*   rowTot = histD + 256 * NBLK2;               // 256
    int*   nodeExcl = rowTot + 256;                    // 256
    int*   edgeExcl = nodeExcl + 256;                  // 256
    int*   perm   = edgeExcl + 256;                    // N
    int*   newbase= perm + N_NODES;                    // N
    int*   ptrS   = newbase + N_NODES;                 // N+1

    const int B   = 256;
    const int gGS = 1024;   // grid-stride
    const int gGA = 2048;   // gather (mult of 8)

    // ---- CSR build: LDS counting sort, zero global atomics ----
    histA_kernel<<<ABLOCKS, B, 0, stream>>>(col, histG, gemb, stats3);
    scanS1_kernel<<<NBUCK, B, 0, stream>>>(histG, bsumA);
    scanS3_kernel<<<NBUCK, B, 0, stream>>>(histG, bsumA, bsumX, ptr);
    scatterA_kernel<<<ABLOCKS, B, 0, stream>>>(row, col, ew, histG, EA);
    bucketA_kernel<<<NBUCK, B, 0, stream>>>(EA, bsumX, ptr, dinv);

    // ---- degree sort of nodes (pad-4 edge layout) ----
    histD_kernel<<<NBLK2, B, 0, stream>>>(ptr, histD);
    scanD1_kernel<<<256, 128, 0, stream>>>(histD, rowTot);
    scanD3_kernel<<<256, 128, 0, stream>>>(histD, rowTot, nodeExcl, edgeExcl, ptrS);
    scatterD_kernel<<<NBLK2, B, 0, stream>>>(ptr, histD, nodeExcl, edgeExcl,
                                             perm, ptrS, newbase, srcoff, normh);
    bucketB_kernel<<<NBUCK, B, 0, stream>>>(EA, bsumX, newbase, srcoff, normh);

    float* h3 = node_embs;  // fp32 post-BN output (written by bn_relu_seg)

    // ---- layer 1 ----
    gemm_kernel<IN_F><<<gGS, B, 0, stream>>>(x, W1, dinv, xwh, N_NODES);
    gather_stats_kernel<<<gGA, B, 0, stream>>>(ptrS, perm, srcoff,
                                               (const unsigned int*)normh, xwh,
                                               dinv, b1, hpl, stats3, N_NODES);

    // ---- layer 2 (BN1+ReLU fused into MFMA GEMM; fp16 h planes in) ----
    gemm_bn_mfma_kernel<<<gGS, B, 0, stream>>>(hpl, W2, stats3, g1, bt1, dinv, xwh, N_NODES);
    gather_stats_kernel<<<gGA, B, 0, stream>>>(ptrS, perm, srcoff,
                                               (const unsigned int*)normh, xwh,
                                               dinv, b2, hpl, stats3 + 128, N_NODES);

    // ---- layer 3 (BN2+ReLU fused into MFMA GEMM) ----
    gemm_bn_mfma_kernel<<<gGS, B, 0, stream>>>(hpl, W3, stats3 + 128, g2, bt2, dinv, xwh, N_NODES);
    gather_stats_kernel<<<gGA, B, 0, stream>>>(ptrS, perm, srcoff,
                                               (const unsigned int*)normh, xwh,
                                               dinv, b3, hpl, stats3 + 256, N_NODES);

    // ---- BN3 + ReLU (from fp16 planes) + node_embs + segment-sum ----
    bn_relu_seg_kernel<<<gGS, B, 0, stream>>>(hpl, h3, stats3 + 256, g3, bt3,
                                              batch, gemb, N_NODES);

    // ---- readout ----
    final_kernel<<<(N_GRAPHS * N_CLS + B - 1) / B, B, 0, stream>>>(gemb, fcW, fcb, out_head);
}